// Round 1
// baseline (643.559 us; speedup 1.0000x reference)
//
#include <hip/hip_runtime.h>
#include <math.h>

// TCN residual block: InstanceNorm1d (no affine) -> ELU -> depthwise conv1d
// (K=3, dilation=1, pad=1) -> +bias -> +residual.
// Shapes: inp (B=32, C=384, T=8192) fp32; weight (C,1,3); bias (C,).
// Strategy: one block per (b,c) row. Row (32 KB) staged in LDS; single global
// read + single global write => memory-bound optimal (~805 MB total traffic).

constexpr int T_LEN = 8192;
constexpr int C_CH  = 384;
constexpr int BLOCK = 256;
constexpr int VPT   = T_LEN / (BLOCK * 4);   // 8 float4 chunks per thread
constexpr float EPS = 1e-5f;

__device__ __forceinline__ float elu_f(float x) {
    return x > 0.0f ? x : expm1f(x);
}

__global__ __launch_bounds__(BLOCK)
void tcn_resblock_kernel(const float* __restrict__ inp,
                         const float* __restrict__ weight,
                         const float* __restrict__ bias,
                         float* __restrict__ out) {
    __shared__ float s_row[T_LEN];     // raw input row (never overwritten)
    __shared__ float s_red[8];         // 4 waves x {sum, sumsq}

    const int row = blockIdx.x;              // row = b * C + c
    const int c   = row % C_CH;
    const float* __restrict__ in_row  = inp + (size_t)row * T_LEN;
    float* __restrict__       out_row = out + (size_t)row * T_LEN;

    const int tid = threadIdx.x;

    // ---- Pass 1: coalesced float4 load -> LDS + registers, accumulate stats
    float4 raw[VPT];
    float sum = 0.0f, sumsq = 0.0f;
#pragma unroll
    for (int k = 0; k < VPT; ++k) {
        const int idx = (k * BLOCK + tid) * 4;           // coalesced
        float4 v = *reinterpret_cast<const float4*>(in_row + idx);
        raw[k] = v;
        *reinterpret_cast<float4*>(s_row + idx) = v;
        sum   += (v.x + v.y) + (v.z + v.w);
        sumsq += (v.x * v.x + v.y * v.y) + (v.z * v.z + v.w * v.w);
    }

    // ---- Wave (64-lane) shuffle reduction, then cross-wave via LDS
#pragma unroll
    for (int off = 32; off > 0; off >>= 1) {
        sum   += __shfl_down(sum,   off, 64);
        sumsq += __shfl_down(sumsq, off, 64);
    }
    const int wave = tid >> 6;
    if ((tid & 63) == 0) {
        s_red[wave * 2]     = sum;
        s_red[wave * 2 + 1] = sumsq;
    }
    __syncthreads();   // also publishes s_row to all threads

    const float tot   = (s_red[0] + s_red[2]) + (s_red[4] + s_red[6]);
    const float totsq = (s_red[1] + s_red[3]) + (s_red[5] + s_red[7]);
    const float inv_t = 1.0f / (float)T_LEN;
    const float mean  = tot * inv_t;
    const float var   = totsq * inv_t - mean * mean;
    const float rstd  = rsqrtf(var + EPS);

    const float w0 = weight[c * 3 + 0];
    const float w1 = weight[c * 3 + 1];
    const float w2 = weight[c * 3 + 2];
    const float bi = bias[c];

    // ---- Pass 2: ELU (registers) + K=3 conv (neighbors from raw LDS) + store
#pragma unroll
    for (int k = 0; k < VPT; ++k) {
        const int idx = (k * BLOCK + tid) * 4;
        const float4 v = raw[k];
        const float e0 = elu_f((v.x - mean) * rstd);
        const float e1 = elu_f((v.y - mean) * rstd);
        const float e2 = elu_f((v.z - mean) * rstd);
        const float e3 = elu_f((v.w - mean) * rstd);

        // left neighbor (t = idx-1) and right neighbor (t = idx+4); zero pad.
        float el = 0.0f, er = 0.0f;
        if (idx != 0)
            el = elu_f((s_row[idx - 1] - mean) * rstd);
        if (idx + 4 != T_LEN)
            er = elu_f((s_row[idx + 4] - mean) * rstd);

        float4 o;
        o.x = w0 * el + w1 * e0 + w2 * e1 + bi + v.x;
        o.y = w0 * e0 + w1 * e1 + w2 * e2 + bi + v.y;
        o.z = w0 * e1 + w1 * e2 + w2 * e3 + bi + v.z;
        o.w = w0 * e2 + w1 * e3 + w2 * er + bi + v.w;
        *reinterpret_cast<float4*>(out_row + idx) = o;   // coalesced
    }
}

extern "C" void kernel_launch(void* const* d_in, const int* in_sizes, int n_in,
                              void* d_out, int out_size, void* d_ws, size_t ws_size,
                              hipStream_t stream) {
    const float* inp    = (const float*)d_in[0];
    const float* weight = (const float*)d_in[1];
    const float* bias   = (const float*)d_in[2];
    float* out          = (float*)d_out;

    const int rows = in_sizes[0] / T_LEN;   // B * C = 12288
    tcn_resblock_kernel<<<rows, BLOCK, 0, stream>>>(inp, weight, bias, out);
}